// Round 14
// baseline (398.781 us; speedup 1.0000x reference)
//
#include <hip/hip_runtime.h>
#include <hip/hip_bf16.h>

#define BATCH 8
#define NH 12
#define DIM 768
#define HD 64
#define NQ 1568       // 8*14*14
#define TT 8
#define HH_ 14
#define WW_ 14
#define LK 392        // 8*7*7
#define LKP 416       // padded V^T row pitch (13*32), zero tail
#define SCALE 0.125f
#define EPS 1e-5f

// compact qkv layout: [s][bh][n (t*196+y*14+x)][c], QKVS elems per s-third
#define QKVS ((size_t)BATCH * NH * NQ * HD)

// prep kernel block-role partition
#define NB_CAST 2048
#define NB_TQKV 1728      // (3*DIM/32)*(DIM/32) = 72*24
#define NB_TPROJ 576      // 24*24
#define NB_ZERO 64
#define NB_WPOOL 21
#define NB_RCAT 10        // 80*32 float2 -> bf16 Rcat table (rows 67..79 zero)

// pool kernel block-role partition (4 row-waves per block)
#define NB_PQ 2688        // 96*8*14/4
#define NB_PK 1344        // 96*8*7/4

typedef __bf16 bf16x8 __attribute__((ext_vector_type(8)));
typedef float f32x4 __attribute__((ext_vector_type(4)));

__device__ inline ushort f2bf(float f) {
  __bf16 h = (__bf16)f;              // native v_cvt (RNE), 1 VALU op
  return __builtin_bit_cast(ushort, h);
}
__device__ inline float bf2f(ushort v) { return __uint_as_float((uint)v << 16); }

// bijective XCD-chunk swizzle (m204). Kept for GEMMs (rest-of-pipeline
// 272->266us r11->r12). NOT for attn (r12: FETCH -3.3x but dur +5.5us).
__device__ inline int xcd_swz(int flat, int nwg) {
  int q = nwg >> 3, r = nwg & 7;
  int xcd = flat & 7, idx = flat >> 3;
  return (xcd < r ? xcd * (q + 1) : r * (q + 1) + (xcd - r) * q) + idx;
}

// async global->LDS, 16B per lane; LDS dest = wave-uniform base + lane*16
__device__ inline void gload_lds16(const ushort* g, ushort* l) {
  __builtin_amdgcn_global_load_lds(
      (const __attribute__((address_space(1))) void*)g,
      (__attribute__((address_space(3))) void*)l, 16, 0, 0);
}

// ---------------- merged prep: cast | w transposes | zero vT | wpool | rcat ----------------
__global__ __launch_bounds__(256) void prep_kernel(
    const float* __restrict__ x, const float* __restrict__ w_qkv,
    const float* __restrict__ w_proj,
    const float* __restrict__ wq, const float* __restrict__ wk,
    const float* __restrict__ wv,
    const float* __restrict__ Rh, const float* __restrict__ Rw,
    const float* __restrict__ Rt,
    ushort* __restrict__ xb, ushort* __restrict__ wqkvT,
    ushort* __restrict__ wprojT, float* __restrict__ wT,
    ushort* __restrict__ rcatB,
    uint4* __restrict__ zp, int nzero16, int ncast4) {
  __shared__ float tile[32][33];
  int bid = blockIdx.x;
  const int tid = threadIdx.x;
  if (bid < NB_CAST) {
    for (int i = bid * 256 + tid; i < ncast4; i += NB_CAST * 256) {
      float4 v = *(const float4*)(x + (size_t)i * 4);
      *(ushort4*)(xb + (size_t)i * 4) =
          make_ushort4(f2bf(v.x), f2bf(v.y), f2bf(v.z), f2bf(v.w));
    }
    return;
  }
  bid -= NB_CAST;
  if (bid < NB_TQKV + NB_TPROJ) {
    const float* in; ushort* outb; int R, C, bx, by;
    if (bid < NB_TQKV) { in = w_qkv; outb = wqkvT; R = DIM; C = 3 * DIM;
                         bx = (bid % 72) * 32; by = (bid / 72) * 32; }
    else { int b2 = bid - NB_TQKV; in = w_proj; outb = wprojT; R = DIM; C = DIM;
           bx = (b2 % 24) * 32; by = (b2 / 24) * 32; }
    int tx = tid & 31, ty = tid >> 5;
#pragma unroll
    for (int r = 0; r < 4; ++r)
      tile[ty + r * 8][tx] = in[(size_t)(by + ty + r * 8) * C + bx + tx];
    __syncthreads();
#pragma unroll
    for (int r = 0; r < 4; ++r)
      outb[(size_t)(bx + ty + r * 8) * R + by + tx] = f2bf(tile[tx][ty + r * 8]);
    return;
  }
  bid -= NB_TQKV + NB_TPROJ;
  if (bid < NB_ZERO) {
    for (int i = bid * 256 + tid; i < nzero16; i += NB_ZERO * 256)
      zp[i] = make_uint4(0, 0, 0, 0);
    return;
  }
  bid -= NB_ZERO;
  if (bid < NB_WPOOL) {
    int i = bid * 256 + tid;
    if (i < 3 * 27 * 64) {
      int s = i / (27 * 64), r = i % (27 * 64), tap = r / 64, c = r % 64;
      const float* src = (s == 0) ? wq : ((s == 1) ? wk : wv);
      wT[i] = src[c * 27 + tap];
    }
    return;
  }
  bid -= NB_WPOOL;
  {
    // Rcat bf16 table: [n 0..79][k 0..63]; rows 67..79 zero
    int e = bid * 256 + tid;
    if (e < 80 * 32) {
      int n = e >> 5, k2 = (e & 31) * 2;
      float2 v;
      if (n < 26)      v = *(const float2*)(Rh + (size_t)n * 64 + k2);
      else if (n < 52) v = *(const float2*)(Rw + (size_t)(n - 26) * 64 + k2);
      else if (n < 67) v = *(const float2*)(Rt + (size_t)(n - 52) * 64 + k2);
      else             v = make_float2(0.f, 0.f);
      *(ushort2*)&rcatB[n * 64 + k2] = make_ushort2(f2bf(v.x), f2bf(v.y));
    }
  }
}

// ---------------- bf16 MFMA GEMM: 2-phase double-buffered (T3-minimal) ------
template<int EPI>
__global__ __launch_bounds__(256) void gemm_mfma(const ushort* __restrict__ A,
                                                 const ushort* __restrict__ Bt,
                                                 const float* __restrict__ bias,
                                                 float* __restrict__ outf,
                                                 ushort* __restrict__ outp,
                                                 int M, int N, int K) {
  __shared__ ushort As[2][128 * 32];   // linear pitch 32 (global_load_lds dest)
  __shared__ ushort Bs[2][128 * 32];
  const int tid = threadIdx.x;
  const int wave = tid >> 6, lane = tid & 63;
  const int quad = lane >> 4, l16 = lane & 15;
  const int nbx = gridDim.x;
  const int flat = blockIdx.y * nbx + blockIdx.x;
  const int swz = xcd_swz(flat, nbx * gridDim.y);
  const int row0 = (swz / nbx) * 128;
  const int col0 = (swz % nbx) * 128;
  const int wm = (wave & 1) * 64;
  const int wn = (wave >> 1) * 64;

  f32x4 acc[4][4];
#pragma unroll
  for (int i = 0; i < 4; ++i)
#pragma unroll
    for (int j = 0; j < 4; ++j) acc[i][j] = (f32x4){0.f, 0.f, 0.f, 0.f};

  // staging geometry: wave w issue i covers rows i*64 + w*16 + (lane>>2), col (lane&3)*8
  const int srow = (wave << 4) + (lane >> 2);
  const int scol = (lane & 3) << 3;
  const ushort* gA = A + (size_t)(row0 + srow) * K + scol;
  const ushort* gB = Bt + (size_t)(col0 + srow) * K + scol;

  // prologue: stage tile 0 into buf 0
  gload_lds16(gA, &As[0][wave * 512]);
  gload_lds16(gA + (size_t)64 * K, &As[0][wave * 512 + 2048]);
  gload_lds16(gB, &Bs[0][wave * 512]);
  gload_lds16(gB + (size_t)64 * K, &Bs[0][wave * 512 + 2048]);
  __syncthreads();                       // drains prologue stage (vmcnt 0)

  int cur = 0;
  for (int k0 = 0; k0 < K; k0 += 32) {
    if (k0 + 32 < K) {                   // issue next tile into other buffer
      int nb = cur ^ 1;
      gload_lds16(gA + k0 + 32, &As[nb][wave * 512]);
      gload_lds16(gA + (size_t)64 * K + k0 + 32, &As[nb][wave * 512 + 2048]);
      gload_lds16(gB + k0 + 32, &Bs[nb][wave * 512]);
      gload_lds16(gB + (size_t)64 * K + k0 + 32, &Bs[nb][wave * 512 + 2048]);
    }
    bf16x8 af[4], bfr[4];
#pragma unroll
    for (int i = 0; i < 4; ++i)
      af[i] = *(const bf16x8*)&As[cur][(wm + i * 16 + l16) * 32 + quad * 8];
#pragma unroll
    for (int j = 0; j < 4; ++j)
      bfr[j] = *(const bf16x8*)&Bs[cur][(wn + j * 16 + l16) * 32 + quad * 8];
#pragma unroll
    for (int i = 0; i < 4; ++i)
#pragma unroll
      for (int j = 0; j < 4; ++j)
        acc[i][j] = __builtin_amdgcn_mfma_f32_16x16x32_bf16(af[i], bfr[j], acc[i][j], 0, 0, 0);
    __syncthreads();                     // drains stage (vmcnt0) + all lgkm
    cur ^= 1;
  }

#pragma unroll
  for (int i = 0; i < 4; ++i) {
#pragma unroll
    for (int j = 0; j < 4; ++j) {
      int col = col0 + wn + j * 16 + l16;
      float bv = bias[col];
#pragma unroll
      for (int r = 0; r < 4; ++r) {
        int row = row0 + wm + i * 16 + quad * 4 + r;
        float val = acc[i][j][r] + bv;
        if (EPI == 0) {
          outf[(size_t)row * N + col] = val;
        } else {
          int b = row / NQ, nn = row % NQ;
          int s = col / DIM, rr = col % DIM;
          int h = rr >> 6, cc = rr & 63;
          size_t pidx = (((size_t)s * BATCH * NH + b * NH + h) * NQ + nn) * (size_t)HD + cc;
          outp[pidx] = f2bf(val);
        }
      }
    }
  }
}

// ---------------- row-per-wave depthwise pool + LayerNorm(64) -> bf16 ----------------
template<int SW, int OWW, int VT>
__device__ __forceinline__ void pool_body(int wid, int lane,
                                          const ushort* __restrict__ in,
                                          ushort* __restrict__ out,
                                          const float* __restrict__ wT,
                                          const float* __restrict__ g,
                                          const float* __restrict__ bb,
                                          float oscale) {
  const int OH = OWW;               // square spatial output
  const int rowsTot = BATCH * NH * TT * OH;
  if (wid >= rowsTot) return;
  const int bh = wid / (TT * OH);
  const int rr = wid % (TT * OH);
  const int ot = rr / OH, oy = rr % OH;
  const int c = lane;

  float wv[27];
#pragma unroll
  for (int i = 0; i < 27; ++i) wv[i] = wT[i * 64 + c];

  float acc[OWW];
#pragma unroll
  for (int o = 0; o < OWW; ++o) acc[o] = 0.f;

  const ushort* bhbase = in + (size_t)bh * NQ * HD + c;
#pragma unroll
  for (int dt = 0; dt < 3; ++dt) {
    int tt = ot + dt - 1;
    if (tt < 0 || tt >= TT) continue;
#pragma unroll
    for (int dy = 0; dy < 3; ++dy) {
      int yy = oy * SW + dy - 1;
      if (yy < 0 || yy >= HH_) continue;
      const ushort* rowb = bhbase + (size_t)(tt * (HH_ * WW_) + yy * WW_) * HD;
      const float* wrow = &wv[(dt * 3 + dy) * 3];
#pragma unroll
      for (int xx = 0; xx < WW_; ++xx) {
        float v = bf2f(rowb[(size_t)xx * HD]);
#pragma unroll
        for (int dx = 0; dx < 3; ++dx) {
          int num = xx + 1 - dx;           // = ox*SW
          if (SW == 1) {
            if (num >= 0 && num < OWW) acc[num] += v * wrow[dx];
          } else {
            if (num >= 0 && (num & 1) == 0 && (num >> 1) < OWW)
              acc[num >> 1] += v * wrow[dx];
          }
        }
      }
    }
  }

  // LayerNorm over c (cross-lane) + store, per output
#pragma unroll
  for (int o = 0; o < OWW; ++o) {
    float a = acc[o];
    float s = a;
#pragma unroll
    for (int off = 32; off; off >>= 1) s += __shfl_xor(s, off, 64);
    float mean = s * (1.f / 64.f);
    float d = a - mean;
    float vs = d * d;
#pragma unroll
    for (int off = 32; off; off >>= 1) vs += __shfl_xor(vs, off, 64);
    float inv = rsqrtf(vs * (1.f / 64.f) + EPS);
    float res = (d * inv * g[c] + bb[c]) * oscale;
    int opos = (ot * OH + oy) * OWW + o;
    if (VT == 0) out[((size_t)bh * (TT * OH * OWW) + opos) * HD + c] = f2bf(res);
    else         out[((size_t)bh * HD + c) * LKP + opos] = f2bf(res);
  }
}

// merged q/k/v pool: block-role dispatch
__global__ __launch_bounds__(256) void pool_all(
    const ushort* __restrict__ qkvb,
    ushort* __restrict__ qpb, ushort* __restrict__ kpb, ushort* __restrict__ vTb,
    const float* __restrict__ wT,
    const float* __restrict__ gq, const float* __restrict__ bq,
    const float* __restrict__ gk, const float* __restrict__ bk,
    const float* __restrict__ gv, const float* __restrict__ bv) {
  const int bid = blockIdx.x;
  const int wl = threadIdx.x >> 6, lane = threadIdx.x & 63;
  if (bid < NB_PQ) {
    pool_body<1, 14, 0>(bid * 4 + wl, lane, qkvb, qpb, wT, gq, bq, 1.0f);
  } else if (bid < NB_PQ + NB_PK) {
    pool_body<2, 7, 0>((bid - NB_PQ) * 4 + wl, lane, qkvb + QKVS, kpb,
                       wT + 27 * 64, gk, bk, SCALE);
  } else {
    pool_body<2, 7, 1>((bid - NB_PQ - NB_PK) * 4 + wl, lane, qkvb + 2 * QKVS, vTb,
                       wT + 2 * 27 * 64, gv, bv, 1.0f);
  }
}

// ---------------- MFMA attention: 32 queries/block, 8 waves (512 thr) ----------------
// r14: q-halves split ACROSS waves — wave w = (tt = w>>2 q-half, wq = w&3
// k-tile group). Per-wave state halves: acc[7] (28 VGPR) + af[2] (8) vs
// acc[7][2]+af[2][2] (72) -> natural VGPR ~60-75 -> 6-8 waves/SIMD (was 4 at
// 104 VGPR). Per-wave serial chain (MFMAs, exp, logits) also halves. K/V
// fragment loads duplicate x2 across tt-waves (L2-hot). PV splits 8-way as
// (tt, colgroup) — no cross-wave reduction. Rel tasks: primary nt=wq, rep
// nt=4 on wq==0, each wave using its own tt's af; scatter map unchanged.
// Softmax without max-pass (bounded logits). 2 barriers.
// NOTE: do NOT cap VGPR via __launch_bounds__ min-waves (r7 spill). Canaries:
// WRITE_SIZE 18.8 MB, VGPR <= 85.
__global__ __launch_bounds__(512) void attn_mfma(const ushort* __restrict__ qp,
                                                 const ushort* __restrict__ kp,
                                                 const ushort* __restrict__ vT,
                                                 const ushort* __restrict__ rcatB,
                                                 ushort* __restrict__ outb) {
  __shared__ ushort sP[32][424];     // pitch 424: P-read (b128) spreads all banks
  __shared__ float sRelT[24][36];
  __shared__ float sSum[32][4];
  const int qb = blockIdx.x;        // 0..48
  const int bh = blockIdx.y;        // 0..95
  const int b = bh / NH, h = bh % NH;
  const int tid = threadIdx.x;
  const int w = tid >> 6, lane = tid & 63;
  const int wq = w & 3, tt = w >> 2;
  const int quad = lane >> 4, l16 = lane & 15;
  const int q0 = qb * 32;

  // zero P pad cols 400..415
  if (tid < 64) {
    int row = tid >> 1, seg = tid & 1;
    *(uint4*)&sP[row][400 + seg * 8] = make_uint4(0, 0, 0, 0);
  }

  // Q A-fragments for this wave's q-half (4x redundant per tt, L2-hot)
  const ushort* qbase = qp + ((size_t)bh * NQ + q0 + tt * 16) * HD;
  bf16x8 af[2];
  af[0] = *(const bf16x8*)(qbase + (size_t)l16 * HD + quad * 8);
  af[1] = *(const bf16x8*)(qbase + (size_t)l16 * HD + 32 + quad * 8);

  f32x4 acc[7];
#pragma unroll
  for (int c = 0; c < 7; ++c) acc[c] = (f32x4){0.f, 0.f, 0.f, 0.f};

  // ---- QK^T: wave computes its tt-half for tiles tg = c*4+wq ----
  const ushort* kbase = kp + (size_t)bh * LK * HD;
#pragma unroll
  for (int c = 0; c < 7; ++c) {
    int tg = c * 4 + wq;
    if (tg < 25) {
      int kg = tg * 16 + l16;
      int kgc = kg < LK ? kg : (LK - 1);   // clamp; masked below
      const ushort* krow = kbase + (size_t)kgc * HD;
      bf16x8 b0 = *(const bf16x8*)(krow + quad * 8);
      bf16x8 b1 = *(const bf16x8*)(krow + 32 + quad * 8);
      acc[c] = __builtin_amdgcn_mfma_f32_16x16x32_bf16(af[0], b0, acc[c], 0, 0, 0);
      acc[c] = __builtin_amdgcn_mfma_f32_16x16x32_bf16(af[1], b1, acc[c], 0, 0, 0);
    }
  }

  // ---- rel MFMA: primary nt = wq; rep nt=4 on wq==0 (both tt covered) ----
#pragma unroll
  for (int rep = 0; rep < 2; ++rep) {
    if (rep == 1 && wq != 0) break;
    int nt = (rep == 0) ? wq : 4;
    f32x4 racc = (f32x4){0.f, 0.f, 0.f, 0.f};
#pragma unroll
    for (int ks = 0; ks < 2; ++ks) {
      bf16x8 bfr = *(const bf16x8*)(rcatB + (size_t)(nt * 16 + l16) * 64 + ks * 32 + quad * 8);
      racc = __builtin_amdgcn_mfma_f32_16x16x32_bf16(af[ks], bfr, racc, 0, 0, 0);
    }
    int c = nt * 16 + l16;
#pragma unroll
    for (int r = 0; r < 4; ++r) {
      int ql = tt * 16 + quad * 4 + r;         // local q row
      int n_ = q0 + ql;
      int t3 = n_ / 196, r2 = n_ % 196, y = r2 / 14, x = r2 % 14;
      float val = racc[r];
      if (c < 26) {
        int dy = y + 12 - c;
        if (dy >= 0 && dy <= 12 && (dy & 1) == 0) sRelT[dy >> 1][ql] = val;
      } else if (c < 52) {
        int dx = x + 12 - (c - 26);
        if (dx >= 0 && dx <= 12 && (dx & 1) == 0) sRelT[7 + (dx >> 1)][ql] = val;
      } else if (c < 67) {
        int dt = t3 + 7 - (c - 52);
        if (dt >= 0 && dt <= 7) sRelT[14 + dt][ql] = val;
      }
    }
  }
  __syncthreads();   // barrier 1: sRelT + sP pad visible

  // ---- logits: rel bias add only (K pre-scaled) ----
#pragma unroll
  for (int c = 0; c < 7; ++c) {
    int tg = c * 4 + wq;
    int kg = tg * 16 + l16;
    if (tg < 25) {
      int kgc = kg < LK ? kg : 0;
      bool ok = kg < LK;
      int kt = kgc / 49, kyx = kgc % 49, ky = kyx / 7, kx = kyx % 7;
      f32x4 bh4 = *(const f32x4*)&sRelT[ky][tt * 16 + quad * 4];
      f32x4 bw4 = *(const f32x4*)&sRelT[7 + kx][tt * 16 + quad * 4];
      f32x4 bt4 = *(const f32x4*)&sRelT[14 + kt][tt * 16 + quad * 4];
#pragma unroll
      for (int r = 0; r < 4; ++r)
        acc[c][r] = ok ? (acc[c][r] + bh4[r] + bw4[r] + bt4[r]) : -1e30f;
    } else {
#pragma unroll
      for (int r = 0; r < 4; ++r) acc[c][r] = -1e30f;
    }
  }

  // ---- exp (no max shift), partial sums, P write ----
  float psum[4];
#pragma unroll
  for (int r = 0; r < 4; ++r) psum[r] = 0.f;
#pragma unroll
  for (int c = 0; c < 7; ++c)
#pragma unroll
    for (int r = 0; r < 4; ++r) {
      float e = __expf(acc[c][r]);       // exp(-1e30) == 0 for masked slots
      acc[c][r] = e;
      psum[r] += e;
    }
#pragma unroll
  for (int r = 0; r < 4; ++r) {
    float s = psum[r];
#pragma unroll
    for (int off = 1; off < 16; off <<= 1) s += __shfl_xor(s, off, 64);
    psum[r] = s;
  }
  if (l16 == 0) {
#pragma unroll
    for (int r = 0; r < 4; ++r) sSum[tt * 16 + quad * 4 + r][wq] = psum[r];
  }
#pragma unroll
  for (int c = 0; c < 7; ++c) {
    int tg = c * 4 + wq;
    if (tg < 25) {
      int kg = tg * 16 + l16;
#pragma unroll
      for (int r = 0; r < 4; ++r)
        sP[tt * 16 + quad * 4 + r][kg] = f2bf(acc[c][r]);
    }
  }
  __syncthreads();   // barrier 2: sP + sSum ready

  float rinv[4];
#pragma unroll
  for (int r = 0; r < 4; ++r) {
    float4 ss = *(float4*)&sSum[tt * 16 + quad * 4 + r][0];
    rinv[r] = 1.f / (ss.x + ss.y + ss.z + ss.w);
  }

  // ---- PV: wave = (tt rows, wq colgroup); V^T fragments direct from global ----
  f32x4 oacc = (f32x4){0.f, 0.f, 0.f, 0.f};
  const ushort* vrow = vT + ((size_t)bh * HD + wq * 16 + l16) * LKP;
#pragma unroll
  for (int s = 0; s < 13; ++s) {
    int kb = s * 32;
    bf16x8 vb = *(const bf16x8*)(vrow + kb + quad * 8);
    bf16x8 pa = *(const bf16x8*)&sP[tt * 16 + l16][kb + quad * 8];
    oacc = __builtin_amdgcn_mfma_f32_16x16x32_bf16(pa, vb, oacc, 0, 0, 0);
  }

#pragma unroll
  for (int r = 0; r < 4; ++r) {
    int q = q0 + tt * 16 + quad * 4 + r;
    outb[((size_t)b * NQ + q) * DIM + h * HD + wq * 16 + l16] = f2bf(oacc[r] * rinv[r]);
  }
}

// ---------------- launch ----------------
extern "C" void kernel_launch(void* const* d_in, const int* in_sizes, int n_in,
                              void* d_out, int out_size, void* d_ws, size_t ws_size,
                              hipStream_t stream) {
  const float* x        = (const float*)d_in[0];
  const float* w_qkv    = (const float*)d_in[1];
  const float* b_qkv    = (const float*)d_in[2];
  const float* pool_q_w = (const float*)d_in[3];
  const float* pool_k_w = (const float*)d_in[4];
  const float* pool_v_w = (const float*)d_in[5];
  const float* norm_q_g = (const float*)d_in[6];
  const float* norm_q_b = (const float*)d_in[7];
  const float* norm_k_g = (const float*)d_in[8];
  const float* norm_k_b = (const float*)d_in[9];
  const float* norm_v_g = (const float*)d_in[10];
  const float* norm_v_b = (const float*)d_in[11];
  const float* rel_h    = (const float*)d_in[12];
  const float* rel_w    = (const float*)d_in[13];
  const float* rel_t    = (const float*)d_in[14];
  const float* w_proj   = (const float*)d_in[15];
  const float* b_proj   = (const float*)d_in[16];
  float* out = (float*)d_out;

  const size_t NT  = (size_t)BATCH * NH * NQ * HD;
  const size_t LKT = (size_t)BATCH * NH * LK * HD;
  const size_t LKV = (size_t)BATCH * NH * HD * LKP;   // padded V^T

  ushort* qkvb = (ushort*)d_ws;                 // 3*QKVS bf16 (compact)
  ushort* qpb  = qkvb + 3 * QKVS;               // NT bf16
  ushort* kpb  = qpb + NT;                      // LKT bf16
  ushort* vTb  = kpb + LKT;                     // LKV bf16 ([bh][c][kpos], pitch LKP)
  ushort* wqkvT = vTb + LKV;
  ushort* wprojT = wqkvT + (size_t)DIM * 3 * DIM;
  float*  wpoolT = (float*)(wprojT + (size_t)DIM * DIM);
  ushort* rcatB = (ushort*)(wpoolT + 3 * 27 * 64);  // 80*64 bf16 Rcat table
  ushort* xb = qpb;                   // overlay: dead before pool writes qpb
  ushort* attn_outb = qkvb;           // overlay: qkvb dead after pools

  const int M = BATCH * NQ;  // 12544

  prep_kernel<<<NB_CAST + NB_TQKV + NB_TPROJ + NB_ZERO + NB_WPOOL + NB_RCAT,
                256, 0, stream>>>(
      x, w_qkv, w_proj, pool_q_w, pool_k_w, pool_v_w, rel_h, rel_w, rel_t,
      xb, wqkvT, wprojT, wpoolT, rcatB,
      (uint4*)vTb, (int)(LKV * 2 / 16), M * DIM / 4);

  gemm_mfma<1><<<dim3(3 * DIM / 128, M / 128), 256, 0, stream>>>(
      xb, wqkvT, b_qkv, nullptr, qkvb, M, 3 * DIM, DIM);

  pool_all<<<NB_PQ + 2 * NB_PK, 256, 0, stream>>>(
      qkvb, qpb, kpb, vTb, wpoolT,
      norm_q_g, norm_q_b, norm_k_g, norm_k_b, norm_v_g, norm_v_b);

  attn_mfma<<<dim3(49, BATCH * NH), 512, 0, stream>>>(
      qpb, kpb, vTb, rcatB, attn_outb);

  gemm_mfma<0><<<dim3(DIM / 128, M / 128), 256, 0, stream>>>(
      attn_outb, wprojT, b_proj, out, nullptr, M, DIM, DIM);
}

// Round 15
// 370.535 us; speedup vs baseline: 1.0762x; 1.0762x over previous
//
#include <hip/hip_runtime.h>
#include <hip/hip_bf16.h>

#define BATCH 8
#define NH 12
#define DIM 768
#define HD 64
#define NQ 1568       // 8*14*14
#define TT 8
#define HH_ 14
#define WW_ 14
#define LK 392        // 8*7*7
#define LKP 416       // padded V^T row pitch (13*32), zero tail
#define SCALE 0.125f
#define EPS 1e-5f

// compact qkv layout: [s][bh][n (t*196+y*14+x)][c], QKVS elems per s-third
#define QKVS ((size_t)BATCH * NH * NQ * HD)

// prep kernel block-role partition
#define NB_CAST 2048
#define NB_TQKV 1728      // (3*DIM/32)*(DIM/32) = 72*24
#define NB_TPROJ 576      // 24*24
#define NB_ZERO 64
#define NB_WPOOL 21
#define NB_RCAT 10        // 80*32 float2 -> bf16 Rcat table (rows 67..79 zero)

// pool kernel block-role partition (4 row-waves per block)
#define NB_PQ 2688        // 96*8*14/4
#define NB_PK 1344        // 96*8*7/4

typedef __bf16 bf16x8 __attribute__((ext_vector_type(8)));
typedef float f32x4 __attribute__((ext_vector_type(4)));

__device__ inline ushort f2bf(float f) {
  __bf16 h = (__bf16)f;              // native v_cvt (RNE), 1 VALU op
  return __builtin_bit_cast(ushort, h);
}
__device__ inline float bf2f(ushort v) { return __uint_as_float((uint)v << 16); }

// bijective XCD-chunk swizzle (m204). Kept for GEMMs (rest-of-pipeline
// 272->266us r11->r12). NOT for attn (r12: FETCH -3.3x but dur +5.5us —
// attn is not traffic-bound; r14: 2x occupancy also SLOWER — not
// latency-hiding-bound either. The r13 shape (fat waves, deep per-wave ILP,
// 4 waves/SIMD) is the operating point).
__device__ inline int xcd_swz(int flat, int nwg) {
  int q = nwg >> 3, r = nwg & 7;
  int xcd = flat & 7, idx = flat >> 3;
  return (xcd < r ? xcd * (q + 1) : r * (q + 1) + (xcd - r) * q) + idx;
}

// async global->LDS, 16B per lane; LDS dest = wave-uniform base + lane*16
__device__ inline void gload_lds16(const ushort* g, ushort* l) {
  __builtin_amdgcn_global_load_lds(
      (const __attribute__((address_space(1))) void*)g,
      (__attribute__((address_space(3))) void*)l, 16, 0, 0);
}

// ---------------- merged prep: cast | w transposes | zero vT | wpool | rcat ----------------
__global__ __launch_bounds__(256) void prep_kernel(
    const float* __restrict__ x, const float* __restrict__ w_qkv,
    const float* __restrict__ w_proj,
    const float* __restrict__ wq, const float* __restrict__ wk,
    const float* __restrict__ wv,
    const float* __restrict__ Rh, const float* __restrict__ Rw,
    const float* __restrict__ Rt,
    ushort* __restrict__ xb, ushort* __restrict__ wqkvT,
    ushort* __restrict__ wprojT, float* __restrict__ wT,
    ushort* __restrict__ rcatB,
    uint4* __restrict__ zp, int nzero16, int ncast4) {
  __shared__ float tile[32][33];
  int bid = blockIdx.x;
  const int tid = threadIdx.x;
  if (bid < NB_CAST) {
    for (int i = bid * 256 + tid; i < ncast4; i += NB_CAST * 256) {
      float4 v = *(const float4*)(x + (size_t)i * 4);
      *(ushort4*)(xb + (size_t)i * 4) =
          make_ushort4(f2bf(v.x), f2bf(v.y), f2bf(v.z), f2bf(v.w));
    }
    return;
  }
  bid -= NB_CAST;
  if (bid < NB_TQKV + NB_TPROJ) {
    const float* in; ushort* outb; int R, C, bx, by;
    if (bid < NB_TQKV) { in = w_qkv; outb = wqkvT; R = DIM; C = 3 * DIM;
                         bx = (bid % 72) * 32; by = (bid / 72) * 32; }
    else { int b2 = bid - NB_TQKV; in = w_proj; outb = wprojT; R = DIM; C = DIM;
           bx = (b2 % 24) * 32; by = (b2 / 24) * 32; }
    int tx = tid & 31, ty = tid >> 5;
#pragma unroll
    for (int r = 0; r < 4; ++r)
      tile[ty + r * 8][tx] = in[(size_t)(by + ty + r * 8) * C + bx + tx];
    __syncthreads();
#pragma unroll
    for (int r = 0; r < 4; ++r)
      outb[(size_t)(bx + ty + r * 8) * R + by + tx] = f2bf(tile[tx][ty + r * 8]);
    return;
  }
  bid -= NB_TQKV + NB_TPROJ;
  if (bid < NB_ZERO) {
    for (int i = bid * 256 + tid; i < nzero16; i += NB_ZERO * 256)
      zp[i] = make_uint4(0, 0, 0, 0);
    return;
  }
  bid -= NB_ZERO;
  if (bid < NB_WPOOL) {
    int i = bid * 256 + tid;
    if (i < 3 * 27 * 64) {
      int s = i / (27 * 64), r = i % (27 * 64), tap = r / 64, c = r % 64;
      const float* src = (s == 0) ? wq : ((s == 1) ? wk : wv);
      wT[i] = src[c * 27 + tap];
    }
    return;
  }
  bid -= NB_WPOOL;
  {
    // Rcat bf16 table: [n 0..79][k 0..63]; rows 67..79 zero
    int e = bid * 256 + tid;
    if (e < 80 * 32) {
      int n = e >> 5, k2 = (e & 31) * 2;
      float2 v;
      if (n < 26)      v = *(const float2*)(Rh + (size_t)n * 64 + k2);
      else if (n < 52) v = *(const float2*)(Rw + (size_t)(n - 26) * 64 + k2);
      else if (n < 67) v = *(const float2*)(Rt + (size_t)(n - 52) * 64 + k2);
      else             v = make_float2(0.f, 0.f);
      *(ushort2*)&rcatB[n * 64 + k2] = make_ushort2(f2bf(v.x), f2bf(v.y));
    }
  }
}

// ---------------- bf16 MFMA GEMM: 2-phase double-buffered (T3-minimal) ------
template<int EPI>
__global__ __launch_bounds__(256) void gemm_mfma(const ushort* __restrict__ A,
                                                 const ushort* __restrict__ Bt,
                                                 const float* __restrict__ bias,
                                                 float* __restrict__ outf,
                                                 ushort* __restrict__ outp,
                                                 int M, int N, int K) {
  __shared__ ushort As[2][128 * 32];   // linear pitch 32 (global_load_lds dest)
  __shared__ ushort Bs[2][128 * 32];
  const int tid = threadIdx.x;
  const int wave = tid >> 6, lane = tid & 63;
  const int quad = lane >> 4, l16 = lane & 15;
  const int nbx = gridDim.x;
  const int flat = blockIdx.y * nbx + blockIdx.x;
  const int swz = xcd_swz(flat, nbx * gridDim.y);
  const int row0 = (swz / nbx) * 128;
  const int col0 = (swz % nbx) * 128;
  const int wm = (wave & 1) * 64;
  const int wn = (wave >> 1) * 64;

  f32x4 acc[4][4];
#pragma unroll
  for (int i = 0; i < 4; ++i)
#pragma unroll
    for (int j = 0; j < 4; ++j) acc[i][j] = (f32x4){0.f, 0.f, 0.f, 0.f};

  // staging geometry: wave w issue i covers rows i*64 + w*16 + (lane>>2), col (lane&3)*8
  const int srow = (wave << 4) + (lane >> 2);
  const int scol = (lane & 3) << 3;
  const ushort* gA = A + (size_t)(row0 + srow) * K + scol;
  const ushort* gB = Bt + (size_t)(col0 + srow) * K + scol;

  // prologue: stage tile 0 into buf 0
  gload_lds16(gA, &As[0][wave * 512]);
  gload_lds16(gA + (size_t)64 * K, &As[0][wave * 512 + 2048]);
  gload_lds16(gB, &Bs[0][wave * 512]);
  gload_lds16(gB + (size_t)64 * K, &Bs[0][wave * 512 + 2048]);
  __syncthreads();                       // drains prologue stage (vmcnt 0)

  int cur = 0;
  for (int k0 = 0; k0 < K; k0 += 32) {
    if (k0 + 32 < K) {                   // issue next tile into other buffer
      int nb = cur ^ 1;
      gload_lds16(gA + k0 + 32, &As[nb][wave * 512]);
      gload_lds16(gA + (size_t)64 * K + k0 + 32, &As[nb][wave * 512 + 2048]);
      gload_lds16(gB + k0 + 32, &Bs[nb][wave * 512]);
      gload_lds16(gB + (size_t)64 * K + k0 + 32, &Bs[nb][wave * 512 + 2048]);
    }
    bf16x8 af[4], bfr[4];
#pragma unroll
    for (int i = 0; i < 4; ++i)
      af[i] = *(const bf16x8*)&As[cur][(wm + i * 16 + l16) * 32 + quad * 8];
#pragma unroll
    for (int j = 0; j < 4; ++j)
      bfr[j] = *(const bf16x8*)&Bs[cur][(wn + j * 16 + l16) * 32 + quad * 8];
#pragma unroll
    for (int i = 0; i < 4; ++i)
#pragma unroll
      for (int j = 0; j < 4; ++j)
        acc[i][j] = __builtin_amdgcn_mfma_f32_16x16x32_bf16(af[i], bfr[j], acc[i][j], 0, 0, 0);
    __syncthreads();                     // drains stage (vmcnt0) + all lgkm
    cur ^= 1;
  }

#pragma unroll
  for (int i = 0; i < 4; ++i) {
#pragma unroll
    for (int j = 0; j < 4; ++j) {
      int col = col0 + wn + j * 16 + l16;
      float bv = bias[col];
#pragma unroll
      for (int r = 0; r < 4; ++r) {
        int row = row0 + wm + i * 16 + quad * 4 + r;
        float val = acc[i][j][r] + bv;
        if (EPI == 0) {
          outf[(size_t)row * N + col] = val;
        } else {
          int b = row / NQ, nn = row % NQ;
          int s = col / DIM, rr = col % DIM;
          int h = rr >> 6, cc = rr & 63;
          size_t pidx = (((size_t)s * BATCH * NH + b * NH + h) * NQ + nn) * (size_t)HD + cc;
          outp[pidx] = f2bf(val);
        }
      }
    }
  }
}

// ---------------- row-per-wave depthwise pool + LayerNorm(64) -> bf16 ----------------
template<int SW, int OWW, int VT>
__device__ __forceinline__ void pool_body(int wid, int lane,
                                          const ushort* __restrict__ in,
                                          ushort* __restrict__ out,
                                          const float* __restrict__ wT,
                                          const float* __restrict__ g,
                                          const float* __restrict__ bb,
                                          float oscale) {
  const int OH = OWW;               // square spatial output
  const int rowsTot = BATCH * NH * TT * OH;
  if (wid >= rowsTot) return;
  const int bh = wid / (TT * OH);
  const int rr = wid % (TT * OH);
  const int ot = rr / OH, oy = rr % OH;
  const int c = lane;

  float wv[27];
#pragma unroll
  for (int i = 0; i < 27; ++i) wv[i] = wT[i * 64 + c];

  float acc[OWW];
#pragma unroll
  for (int o = 0; o < OWW; ++o) acc[o] = 0.f;

  const ushort* bhbase = in + (size_t)bh * NQ * HD + c;
#pragma unroll
  for (int dt = 0; dt < 3; ++dt) {
    int tt = ot + dt - 1;
    if (tt < 0 || tt >= TT) continue;
#pragma unroll
    for (int dy = 0; dy < 3; ++dy) {
      int yy = oy * SW + dy - 1;
      if (yy < 0 || yy >= HH_) continue;
      const ushort* rowb = bhbase + (size_t)(tt * (HH_ * WW_) + yy * WW_) * HD;
      const float* wrow = &wv[(dt * 3 + dy) * 3];
#pragma unroll
      for (int xx = 0; xx < WW_; ++xx) {
        float v = bf2f(rowb[(size_t)xx * HD]);
#pragma unroll
        for (int dx = 0; dx < 3; ++dx) {
          int num = xx + 1 - dx;           // = ox*SW
          if (SW == 1) {
            if (num >= 0 && num < OWW) acc[num] += v * wrow[dx];
          } else {
            if (num >= 0 && (num & 1) == 0 && (num >> 1) < OWW)
              acc[num >> 1] += v * wrow[dx];
          }
        }
      }
    }
  }

  // LayerNorm over c (cross-lane) + store, per output
#pragma unroll
  for (int o = 0; o < OWW; ++o) {
    float a = acc[o];
    float s = a;
#pragma unroll
    for (int off = 32; off; off >>= 1) s += __shfl_xor(s, off, 64);
    float mean = s * (1.f / 64.f);
    float d = a - mean;
    float vs = d * d;
#pragma unroll
    for (int off = 32; off; off >>= 1) vs += __shfl_xor(vs, off, 64);
    float inv = rsqrtf(vs * (1.f / 64.f) + EPS);
    float res = (d * inv * g[c] + bb[c]) * oscale;
    int opos = (ot * OH + oy) * OWW + o;
    if (VT == 0) out[((size_t)bh * (TT * OH * OWW) + opos) * HD + c] = f2bf(res);
    else         out[((size_t)bh * HD + c) * LKP + opos] = f2bf(res);
  }
}

// merged q/k/v pool: block-role dispatch
__global__ __launch_bounds__(256) void pool_all(
    const ushort* __restrict__ qkvb,
    ushort* __restrict__ qpb, ushort* __restrict__ kpb, ushort* __restrict__ vTb,
    const float* __restrict__ wT,
    const float* __restrict__ gq, const float* __restrict__ bq,
    const float* __restrict__ gk, const float* __restrict__ bk,
    const float* __restrict__ gv, const float* __restrict__ bv) {
  const int bid = blockIdx.x;
  const int wl = threadIdx.x >> 6, lane = threadIdx.x & 63;
  if (bid < NB_PQ) {
    pool_body<1, 14, 0>(bid * 4 + wl, lane, qkvb, qpb, wT, gq, bq, 1.0f);
  } else if (bid < NB_PQ + NB_PK) {
    pool_body<2, 7, 0>((bid - NB_PQ) * 4 + wl, lane, qkvb + QKVS, kpb,
                       wT + 27 * 64, gk, bk, SCALE);
  } else {
    pool_body<2, 7, 1>((bid - NB_PQ - NB_PK) * 4 + wl, lane, qkvb + 2 * QKVS, vTb,
                       wT + 2 * 27 * 64, gv, bv, 1.0f);
  }
}

// ---------------- MFMA attention: 32 queries/block, rel bias fused ----------------
// r13 structure (best measured: 104.4us): 4 waves, acc[7][2], 2 barriers,
// rel B-frags direct from prep-built bf16 Rcat global table.
// r15 tweak: prefetch first 4 V fragments BEFORE barrier 1 (+16 VGPR,
// still < 128 cliff) — their L2 latency hides under logits+exp+psum+P-write
// instead of being exposed after barrier 2.
// REJECTED experiments: XCD swizzle (r12: -3.3x FETCH, +5.5us), 8-wave
// occupancy split (r14: 2x occupancy, +28us), VGPR cap (r7: spill).
// Softmax without max-pass (bounded logits). Canaries: WRITE_SIZE 18.8 MB,
// VGPR <= 127.
__global__ __launch_bounds__(256) void attn_mfma(const ushort* __restrict__ qp,
                                                 const ushort* __restrict__ kp,
                                                 const ushort* __restrict__ vT,
                                                 const ushort* __restrict__ rcatB,
                                                 ushort* __restrict__ outb) {
  __shared__ ushort sP[32][424];     // pitch 424: P-read (b128) spreads all banks
  __shared__ float sRelT[24][36];
  __shared__ float sSum[32][4];
  const int qb = blockIdx.x;        // 0..48
  const int bh = blockIdx.y;        // 0..95
  const int b = bh / NH, h = bh % NH;
  const int tid = threadIdx.x;
  const int w = tid >> 6, lane = tid & 63;
  const int quad = lane >> 4, l16 = lane & 15;
  const int q0 = qb * 32;

  // zero P pad cols 400..415
  if (tid < 64) {
    int row = tid >> 1, seg = tid & 1;
    *(uint4*)&sP[row][400 + seg * 8] = make_uint4(0, 0, 0, 0);
  }

  // Q A-fragments direct from global (same for all waves; 4x redundant, tiny)
  const ushort* qbase = qp + ((size_t)bh * NQ + q0) * HD;
  bf16x8 af[2][2];
#pragma unroll
  for (int t = 0; t < 2; ++t) {
    af[t][0] = *(const bf16x8*)(qbase + (size_t)(t * 16 + l16) * HD + quad * 8);
    af[t][1] = *(const bf16x8*)(qbase + (size_t)(t * 16 + l16) * HD + 32 + quad * 8);
  }

  f32x4 acc[7][2];
#pragma unroll
  for (int c = 0; c < 7; ++c)
#pragma unroll
    for (int t = 0; t < 2; ++t) acc[c][t] = (f32x4){0.f, 0.f, 0.f, 0.f};

  // ---- QK^T: wave w owns tiles tg = c*4+w; K B-fragments direct from global ----
  const ushort* kbase = kp + (size_t)bh * LK * HD;
#pragma unroll
  for (int c = 0; c < 7; ++c) {
    int tg = c * 4 + w;
    if (tg < 25) {
      int kg = tg * 16 + l16;
      int kgc = kg < LK ? kg : (LK - 1);   // clamp; masked below
      const ushort* krow = kbase + (size_t)kgc * HD;
      bf16x8 b0 = *(const bf16x8*)(krow + quad * 8);
      bf16x8 b1 = *(const bf16x8*)(krow + 32 + quad * 8);
#pragma unroll
      for (int t = 0; t < 2; ++t) {
        acc[c][t] = __builtin_amdgcn_mfma_f32_16x16x32_bf16(af[t][0], b0, acc[c][t], 0, 0, 0);
        acc[c][t] = __builtin_amdgcn_mfma_f32_16x16x32_bf16(af[t][1], b1, acc[c][t], 0, 0, 0);
      }
    }
  }

  // ---- rel MFMA: tiles nt = w (wave 3 also nt=4); B-frags from global table ----
#pragma unroll
  for (int rep = 0; rep < 2; ++rep) {
    if (rep == 1 && w != 3) break;
    int nt = (rep == 0) ? w : 4;
    f32x4 racc[2];
    racc[0] = (f32x4){0.f, 0.f, 0.f, 0.f};
    racc[1] = (f32x4){0.f, 0.f, 0.f, 0.f};
#pragma unroll
    for (int ks = 0; ks < 2; ++ks) {
      bf16x8 bfr = *(const bf16x8*)(rcatB + (size_t)(nt * 16 + l16) * 64 + ks * 32 + quad * 8);
#pragma unroll
      for (int t = 0; t < 2; ++t)
        racc[t] = __builtin_amdgcn_mfma_f32_16x16x32_bf16(af[t][ks], bfr, racc[t], 0, 0, 0);
    }
    int c = nt * 16 + l16;
#pragma unroll
    for (int t = 0; t < 2; ++t) {
#pragma unroll
      for (int r = 0; r < 4; ++r) {
        int ql = t * 16 + quad * 4 + r;          // local q row 0..31
        int n_ = q0 + ql;
        int t3 = n_ / 196, r2 = n_ % 196, y = r2 / 14, x = r2 % 14;
        float val = racc[t][r];
        if (c < 26) {
          int dy = y + 12 - c;
          if (dy >= 0 && dy <= 12 && (dy & 1) == 0) sRelT[dy >> 1][ql] = val;
        } else if (c < 52) {
          int dx = x + 12 - (c - 26);
          if (dx >= 0 && dx <= 12 && (dx & 1) == 0) sRelT[7 + (dx >> 1)][ql] = val;
        } else if (c < 67) {
          int dt = t3 + 7 - (c - 52);
          if (dt >= 0 && dt <= 7) sRelT[14 + dt][ql] = val;
        }
      }
    }
  }

  // ---- r15: V prefetch (first 4 of 13 fragments) issued pre-barrier; their
  // latency hides under logits+exp+psum+P-write. +16 VGPR, < 128 cliff. ----
  const ushort* vrow = vT + ((size_t)bh * HD + w * 16 + l16) * LKP;
  bf16x8 vpre[4];
#pragma unroll
  for (int s = 0; s < 4; ++s)
    vpre[s] = *(const bf16x8*)(vrow + s * 32 + quad * 8);

  __syncthreads();   // barrier 1: sRelT + sP pad visible

  // ---- logits: rel bias add only (K pre-scaled), one b128 per term per (c,t) ----
#pragma unroll
  for (int c = 0; c < 7; ++c) {
    int tg = c * 4 + w;
    int kg = tg * 16 + l16;
    if (tg < 25) {
      int kgc = kg < LK ? kg : 0;
      bool ok = kg < LK;
      int kt = kgc / 49, kyx = kgc % 49, ky = kyx / 7, kx = kyx % 7;
#pragma unroll
      for (int t = 0; t < 2; ++t) {
        f32x4 bh4 = *(const f32x4*)&sRelT[ky][t * 16 + quad * 4];
        f32x4 bw4 = *(const f32x4*)&sRelT[7 + kx][t * 16 + quad * 4];
        f32x4 bt4 = *(const f32x4*)&sRelT[14 + kt][t * 16 + quad * 4];
#pragma unroll
        for (int r = 0; r < 4; ++r)
          acc[c][t][r] = ok ? (acc[c][t][r] + bh4[r] + bw4[r] + bt4[r]) : -1e30f;
      }
    } else {
#pragma unroll
      for (int t = 0; t < 2; ++t)
#pragma unroll
        for (int r = 0; r < 4; ++r) acc[c][t][r] = -1e30f;
    }
  }

  // ---- exp (no max shift; logits bounded), partial sums, P write ----
  float psum[2][4];
#pragma unroll
  for (int t = 0; t < 2; ++t)
#pragma unroll
    for (int r = 0; r < 4; ++r) psum[t][r] = 0.f;
#pragma unroll
  for (int c = 0; c < 7; ++c) {
#pragma unroll
    for (int t = 0; t < 2; ++t)
#pragma unroll
      for (int r = 0; r < 4; ++r) {
        float e = __expf(acc[c][t][r]);   // exp(-1e30) == 0 for masked slots
        acc[c][t][r] = e;
        psum[t][r] += e;
      }
  }
#pragma unroll
  for (int t = 0; t < 2; ++t)
#pragma unroll
    for (int r = 0; r < 4; ++r) {
      float s = psum[t][r];
#pragma unroll
      for (int off = 1; off < 16; off <<= 1) s += __shfl_xor(s, off, 64);
      psum[t][r] = s;
    }
  if (l16 == 0) {
#pragma unroll
    for (int t = 0; t < 2; ++t)
#pragma unroll
      for (int r = 0; r < 4; ++r) sSum[t * 16 + quad * 4 + r][w] = psum[t][r];
  }
#pragma unroll
  for (int c = 0; c < 7; ++c) {
    int tg = c * 4 + w;
    if (tg < 25) {
      int kg = tg * 16 + l16;
#pragma unroll
      for (int t = 0; t < 2; ++t)
#pragma unroll
        for (int r = 0; r < 4; ++r)
          sP[t * 16 + quad * 4 + r][kg] = f2bf(acc[c][t][r]);
    }
  }
  __syncthreads();   // barrier 2: sP + sSum ready

  float rinv[2][4];
#pragma unroll
  for (int t = 0; t < 2; ++t)
#pragma unroll
    for (int r = 0; r < 4; ++r) {
      float4 ss = *(float4*)&sSum[t * 16 + quad * 4 + r][0];
      rinv[t][r] = 1.f / (ss.x + ss.y + ss.z + ss.w);
    }

  // ---- PV: first 4 V fragments from prefetch regs, rest direct from global ----
  f32x4 oacc[2];
  oacc[0] = (f32x4){0.f, 0.f, 0.f, 0.f};
  oacc[1] = (f32x4){0.f, 0.f, 0.f, 0.f};
#pragma unroll
  for (int s = 0; s < 13; ++s) {
    int kb = s * 32;
    bf16x8 vb = (s < 4) ? vpre[s] : *(const bf16x8*)(vrow + kb + quad * 8);
#pragma unroll
    for (int t = 0; t < 2; ++t) {
      bf16x8 pa = *(const bf16x8*)&sP[t * 16 + l16][kb + quad * 8];
      oacc[t] = __builtin_amdgcn_mfma_f32_16x16x32_bf16(pa, vb, oacc[t], 0, 0, 0);
    }
  }

#pragma unroll
  for (int t = 0; t < 2; ++t)
#pragma unroll
    for (int r = 0; r < 4; ++r) {
      int q = q0 + t * 16 + quad * 4 + r;
      outb[((size_t)b * NQ + q) * DIM + h * HD + w * 16 + l16] = f2bf(oacc[t][r] * rinv[t][r]);
    }
}

// ---------------- launch ----------------
extern "C" void kernel_launch(void* const* d_in, const int* in_sizes, int n_in,
                              void* d_out, int out_size, void* d_ws, size_t ws_size,
                              hipStream_t stream) {
  const float* x        = (const float*)d_in[0];
  const float* w_qkv    = (const float*)d_in[1];
  const float* b_qkv    = (const float*)d_in[2];
  const float* pool_q_w = (const float*)d_in[3];
  const float* pool_k_w = (const float*)d_in[4];
  const float* pool_v_w = (const float*)d_in[5];
  const float* norm_q_g = (const float*)d_in[6];
  const float* norm_q_b = (const float*)d_in[7];
  const float* norm_k_g = (const float*)d_in[8];
  const float* norm_k_b = (const float*)d_in[9];
  const float* norm_v_g = (const float*)d_in[10];
  const float* norm_v_b = (const float*)d_in[11];
  const float* rel_h    = (const float*)d_in[12];
  const float* rel_w    = (const float*)d_in[13];
  const float* rel_t    = (const float*)d_in[14];
  const float* w_proj   = (const float*)d_in[15];
  const float* b_proj   = (const float*)d_in[16];
  float* out = (float*)d_out;

  const size_t NT  = (size_t)BATCH * NH * NQ * HD;
  const size_t LKT = (size_t)BATCH * NH * LK * HD;
  const size_t LKV = (size_t)BATCH * NH * HD * LKP;   // padded V^T

  ushort* qkvb = (ushort*)d_ws;                 // 3*QKVS bf16 (compact)
  ushort* qpb  = qkvb + 3 * QKVS;               // NT bf16
  ushort* kpb  = qpb + NT;                      // LKT bf16
  ushort* vTb  = kpb + LKT;                     // LKV bf16 ([bh][c][kpos], pitch LKP)
  ushort* wqkvT = vTb + LKV;
  ushort* wprojT = wqkvT + (size_t)DIM * 3 * DIM;
  float*  wpoolT = (float*)(wprojT + (size_t)DIM * DIM);
  ushort* rcatB = (ushort*)(wpoolT + 3 * 27 * 64);  // 80*64 bf16 Rcat table
  ushort* xb = qpb;                   // overlay: dead before pool writes qpb
  ushort* attn_outb = qkvb;           // overlay: qkvb dead after pools

  const int M = BATCH * NQ;  // 12544

  prep_kernel<<<NB_CAST + NB_TQKV + NB_TPROJ + NB_ZERO + NB_WPOOL + NB_RCAT,
                256, 0, stream>>>(
      x, w_qkv, w_proj, pool_q_w, pool_k_w, pool_v_w, rel_h, rel_w, rel_t,
      xb, wqkvT, wprojT, wpoolT, rcatB,
      (uint4*)vTb, (int)(LKV * 2 / 16), M * DIM / 4);

  gemm_mfma<1><<<dim3(3 * DIM / 128, M / 128), 256, 0, stream>>>(
      xb, wqkvT, b_qkv, nullptr, qkvb, M, 3 * DIM, DIM);

  pool_all<<<NB_PQ + 2 * NB_PK, 256, 0, stream>>>(
      qkvb, qpb, kpb, vTb, wpoolT,
      norm_q_g, norm_q_b, norm_k_g, norm_k_b, norm_v_g, norm_v_b);

  attn_mfma<<<dim3(49, BATCH * NH), 256, 0, stream>>>(
      qpb, kpb, vTb, rcatB, attn_outb);

  gemm_mfma<0><<<dim3(DIM / 128, M / 128), 256, 0, stream>>>(
      attn_outb, wprojT, b_proj, out, nullptr, M, DIM, DIM);
}